// Round 4
// baseline (497.187 us; speedup 1.0000x reference)
//
#include <hip/hip_runtime.h>
#include <stdint.h>

// Problem constants (match reference)
#define NE   64      // experts
#define HD   2048    // hidden dim
#define ND   512     // difficulty head inner dim
#define NTOK 16384   // B*S = 4*4096

typedef __attribute__((ext_vector_type(4))) float   fv4;
typedef __attribute__((ext_vector_type(8))) short   bf16x8;
typedef __attribute__((ext_vector_type(4))) float   f32x4;

// LDS 16B-unit index: row*4 + (q ^ ((row>>2)&3)).
__device__ inline int swz(int row, int q) {
  return row * 4 + (q ^ ((row >> 2) & 3));
}

// ---------- helpers ----------
__device__ inline unsigned short bf_rne(float x) {
  unsigned int u = __float_as_uint(x);
  return (unsigned short)((u + 0x7FFFu + ((u >> 16) & 1u)) >> 16);
}
__device__ inline float bf_to_f(unsigned short h) {
  return __uint_as_float((unsigned int)h << 16);
}
// exact 3-way truncation split: x == h + m + l (8+8+8 mantissa bits)
__device__ inline void split3(float x, unsigned short& h, unsigned short& m,
                              unsigned short& l) {
  unsigned int u = __float_as_uint(x);
  h = (unsigned short)(u >> 16);
  float r1 = x - __uint_as_float(u & 0xFFFF0000u);
  unsigned int um = __float_as_uint(r1);
  m = (unsigned short)(um >> 16);
  float r2 = r1 - __uint_as_float(um & 0xFFFF0000u);
  l = bf_rne(r2);
}

// async global->LDS 16B copy. Dest = wave-uniform base + lane*16 (all staging
// loops assign lane-consecutive units per wave). Source addr is per-lane.
__device__ inline void gload16(const void* g, void* l) {
  __builtin_amdgcn_global_load_lds(
      (__attribute__((address_space(1))) void*)g,
      (__attribute__((address_space(3))) void*)l, 16, 0, 0);
}

// ---------- K0: fused zero + w1 split + gw split3 (independent writes) ----
__global__ __launch_bounds__(256)
void k_pre(uint4* __restrict__ z16, const float* __restrict__ w1,
           unsigned short* __restrict__ w1h, unsigned short* __restrict__ w1l,
           const float* __restrict__ gw, unsigned short* __restrict__ gh,
           unsigned short* __restrict__ gm, unsigned short* __restrict__ gl) {
  const int b = blockIdx.x, t = threadIdx.x;
  if (b < 1040) {
    // zero lg + x2/tpe/ks_es: 4,260,368 B = 266,273 uint4
    uint4 zz = {0u, 0u, 0u, 0u};
    for (int i = b * 256 + t; i < 266273; i += 1040 * 256) z16[i] = zz;
  } else if (b < 1552) {
    // w1 fp32 -> bf16 hi/lo planes (rne)
    int i = ((b - 1040) * 256 + t) * 8;
    fv4 v0 = *(const fv4*)(w1 + i);
    fv4 v1 = *(const fv4*)(w1 + i + 4);
    union { unsigned short s[8]; uint4 v; } ph, pl;
#pragma unroll
    for (int j = 0; j < 8; ++j) {
      float x = (j < 4) ? v0[j] : v1[j - 4];
      unsigned short h = bf_rne(x);
      ph.s[j] = h;
      pl.s[j] = bf_rne(x - bf_to_f(h));
    }
    *(uint4*)(w1h + i) = ph.v;
    *(uint4*)(w1l + i) = pl.v;
  } else {
    // gw fp32 -> 3 exact bf16 planes (h/m/l truncation split)
    int i = ((b - 1552) * 256 + t) * 8;
    fv4 v0 = *(const fv4*)(gw + i);
    fv4 v1 = *(const fv4*)(gw + i + 4);
    union { unsigned short s[8]; uint4 v; } xh, xm, xl;
#pragma unroll
    for (int j = 0; j < 8; ++j) {
      float x = (j < 4) ? v0[j] : v1[j - 4];
      split3(x, xh.s[j], xm.s[j], xl.s[j]);
    }
    *(uint4*)(gh + i) = xh.v;
    *(uint4*)(gm + i) = xm.v;
    *(uint4*)(gl + i) = xl.v;
  }
}

// ---------- K1: fused gate + difficulty GEMMs, 512-thread pipelined -------
// kind = bid&1 (gate/diff interleaved). 8 waves/block, small per-wave tiles
// (gate 32x16 acc[2], diff 32x64 acc[2][4]) to cut register footprint;
// __launch_bounds__(512,4) -> 4 waves/SIMD. LDS 80KB union, 2 blocks/CU.
// Double-buffered K-steps with ONE barrier each: issue B-DMA(next)+A-load
// (next) BEFORE computing current tile; split+ds_write(next) after MFMAs;
// barrier drain at end (loads had a full compute phase to land).
// Every per-element fp32 chain (MFMA term order, kb order, epilogue sums,
// atomic contributor sets) is bit-identical to the R1-passing kernel.
__global__ __launch_bounds__(512, 4)
void k_main(const float* __restrict__ hs, const unsigned short* __restrict__ gh,
            const unsigned short* __restrict__ gm,
            const unsigned short* __restrict__ gl, float* __restrict__ lg,
            const unsigned short* __restrict__ w1h,
            const unsigned short* __restrict__ w1l, const float* __restrict__ b1,
            const float* __restrict__ w2, float* __restrict__ x2) {
  __shared__ __align__(16) unsigned short smem[40960];  // 80KB union

  const int t = threadIdx.x;
  const int w = t >> 6, l = t & 63, l15 = l & 15, q = l >> 4;
  // A staging: half-unit (4 floats) per thread, 512 threads cover 256 units
  const int u = t >> 1, half = t & 1;
  const int arow = u >> 2, aq = (u & 3) ^ ((u >> 4) & 3);
  const int bid = blockIdx.x;
  const int kind = bid & 1;
  const int idx = bid >> 1;
  const int bx = idx & 1;
  const int tokBase = (idx >> 1) * 64;

  if (kind == 0) {
    // ================= gate body =================
    // buf layout (shorts): [Ah 2048][Am 2048][Al 2048][Bh 2048][Bm 2048][Bl 2048]
    const int k0base = bx * (HD / 2);
    const int waveM = w & 1, waveN = w >> 1;   // wave tile: 32 tok x 16 exp

    int aOff[2];
#pragma unroll
    for (int rt = 0; rt < 2; ++rt)
      aOff[rt] = swz(waveM * 32 + rt * 16 + l15, q) * 8;
    const int bOff = swz(waveN * 16 + l15, q) * 8;

    const float* gAp = hs + (size_t)(tokBase + arow) * HD + k0base + aq * 8 + half * 4;

    // B staging source offsets (pre-swizzled global -> linear LDS)
    const int s0 = (t < 256) ? t : (t - 256);
    const size_t gbB = (size_t)(s0 >> 2) * HD + k0base + ((s0 & 3) ^ ((s0 >> 4) & 3)) * 8;

    f32x4 acc[2] = {};

    // --- prologue: stage kb=0 into buf 0 ---
    {
      unsigned short* base = smem;
      if (t < 256) {
        gload16(gh + gbB, base + 6144 + s0 * 8);
        gload16(gl + gbB, base + 10240 + s0 * 8);
      } else {
        gload16(gm + gbB, base + 8192 + s0 * 8);
      }
      fv4 v = *(const fv4*)gAp;
      union { unsigned short s[4]; uint2 d; } xh, xm, xl;
#pragma unroll
      for (int j = 0; j < 4; ++j) split3(v[j], xh.s[j], xm.s[j], xl.s[j]);
      *(uint2*)&base[u * 8 + half * 4] = xh.d;
      *(uint2*)&base[2048 + u * 8 + half * 4] = xm.d;
      *(uint2*)&base[4096 + u * 8 + half * 4] = xl.d;
    }
    __syncthreads();

    int c = 0;
    for (int kb = 0; kb < 32; ++kb) {
      const bool pf = (kb + 1 < 32);
      fv4 an;
      if (pf) {
        unsigned short* nb = smem + (c ^ 1) * 12288;
        const size_t gb = gbB + (kb + 1) * 32;
        if (t < 256) {
          gload16(gh + gb, nb + 6144 + s0 * 8);
          gload16(gl + gb, nb + 10240 + s0 * 8);
        } else {
          gload16(gm + gb, nb + 8192 + s0 * 8);
        }
        an = *(const fv4*)(gAp + (kb + 1) * 32);
      }
      // compute current tile
      const unsigned short* base = smem + c * 12288;
      bf16x8 vbh = *(const bf16x8*)&base[6144 + bOff];
      bf16x8 vbm = *(const bf16x8*)&base[8192 + bOff];
      bf16x8 vbl = *(const bf16x8*)&base[10240 + bOff];
#pragma unroll
      for (int rt = 0; rt < 2; ++rt) {
        bf16x8 vah = *(const bf16x8*)&base[aOff[rt]];
        bf16x8 vam = *(const bf16x8*)&base[2048 + aOff[rt]];
        bf16x8 val = *(const bf16x8*)&base[4096 + aOff[rt]];
        acc[rt] = __builtin_amdgcn_mfma_f32_16x16x32_bf16(val, vbh, acc[rt], 0, 0, 0);
        acc[rt] = __builtin_amdgcn_mfma_f32_16x16x32_bf16(vah, vbl, acc[rt], 0, 0, 0);
        acc[rt] = __builtin_amdgcn_mfma_f32_16x16x32_bf16(vam, vbm, acc[rt], 0, 0, 0);
        acc[rt] = __builtin_amdgcn_mfma_f32_16x16x32_bf16(vam, vbh, acc[rt], 0, 0, 0);
        acc[rt] = __builtin_amdgcn_mfma_f32_16x16x32_bf16(vah, vbm, acc[rt], 0, 0, 0);
        acc[rt] = __builtin_amdgcn_mfma_f32_16x16x32_bf16(vah, vbh, acc[rt], 0, 0, 0);
      }
      if (pf) {
        unsigned short* nb = smem + (c ^ 1) * 12288;
        union { unsigned short s[4]; uint2 d; } xh, xm, xl;
#pragma unroll
        for (int j = 0; j < 4; ++j) split3(an[j], xh.s[j], xm.s[j], xl.s[j]);
        *(uint2*)&nb[u * 8 + half * 4] = xh.d;
        *(uint2*)&nb[2048 + u * 8 + half * 4] = xm.d;
        *(uint2*)&nb[4096 + u * 8 + half * 4] = xl.d;
      }
      __syncthreads();
      c ^= 1;
    }

#pragma unroll
    for (int rt = 0; rt < 2; ++rt)
#pragma unroll
      for (int i = 0; i < 4; ++i)
        unsafeAtomicAdd(&lg[(size_t)(tokBase + waveM * 32 + rt * 16 + q * 4 + i) * NE +
                            waveN * 16 + l15], acc[rt][i]);
  } else {
    // ================= diff body =================
    // buf layout (shorts): [Ah 2048][Al 2048][Bh 8192][Bl 8192] = 20480/buf
    const int nBase = bx * 256;
    const int waveR = w & 1, waveC = w >> 1;   // wave tile: 32 tok x 64 col

    int aOff[2];
#pragma unroll
    for (int rt = 0; rt < 2; ++rt)
      aOff[rt] = swz(waveR * 32 + rt * 16 + l15, q) * 8;
    int bOff[4];
#pragma unroll
    for (int ct = 0; ct < 4; ++ct)
      bOff[ct] = swz(waveC * 64 + ct * 16 + l15, q) * 8;

    const float* gAp = hs + (size_t)(tokBase + arow) * HD + aq * 8 + half * 4;

    // B staging: 1024 units/plane, 2 per thread per plane
    size_t gbB[2];
#pragma unroll
    for (int j = 0; j < 2; ++j) {
      const int s = t + j * 512;
      gbB[j] = (size_t)(nBase + (s >> 2)) * HD + ((s & 3) ^ ((s >> 4) & 3)) * 8;
    }

    f32x4 acc[2][4] = {};

    // --- prologue: stage kb=0 into buf 0 ---
    {
      unsigned short* base = smem;
#pragma unroll
      for (int j = 0; j < 2; ++j) {
        const int s = t + j * 512;
        gload16(w1h + gbB[j], base + 4096 + s * 8);
        gload16(w1l + gbB[j], base + 12288 + s * 8);
      }
      fv4 v = *(const fv4*)gAp;
      union { unsigned short s[4]; uint2 d; } ph, pl;
#pragma unroll
      for (int j = 0; j < 4; ++j) {
        unsigned short h = bf_rne(v[j]);
        ph.s[j] = h;
        pl.s[j] = bf_rne(v[j] - bf_to_f(h));
      }
      *(uint2*)&base[u * 8 + half * 4] = ph.d;
      *(uint2*)&base[2048 + u * 8 + half * 4] = pl.d;
    }
    __syncthreads();

    int c = 0;
    for (int kb = 0; kb < HD / 32; ++kb) {
      const bool pf = (kb + 1 < HD / 32);
      fv4 an;
      if (pf) {
        unsigned short* nb = smem + (c ^ 1) * 20480;
        const int k0n = (kb + 1) * 32;
#pragma unroll
        for (int j = 0; j < 2; ++j) {
          const int s = t + j * 512;
          gload16(w1h + gbB[j] + k0n, nb + 4096 + s * 8);
          gload16(w1l + gbB[j] + k0n, nb + 12288 + s * 8);
        }
        an = *(const fv4*)(gAp + (kb + 1) * 32);
      }
      // compute current tile
      const unsigned short* base = smem + c * 20480;
      bf16x8 vbh[4], vbl[4];
#pragma unroll
      for (int ct = 0; ct < 4; ++ct) {
        vbh[ct] = *(const bf16x8*)&base[4096 + bOff[ct]];
        vbl[ct] = *(const bf16x8*)&base[12288 + bOff[ct]];
      }
#pragma unroll
      for (int rt = 0; rt < 2; ++rt) {
        bf16x8 vah = *(const bf16x8*)&base[aOff[rt]];
        bf16x8 val = *(const bf16x8*)&base[2048 + aOff[rt]];
#pragma unroll
        for (int ct = 0; ct < 4; ++ct) {
          acc[rt][ct] = __builtin_amdgcn_mfma_f32_16x16x32_bf16(vah, vbh[ct], acc[rt][ct], 0, 0, 0);
          acc[rt][ct] = __builtin_amdgcn_mfma_f32_16x16x32_bf16(vah, vbl[ct], acc[rt][ct], 0, 0, 0);
          acc[rt][ct] = __builtin_amdgcn_mfma_f32_16x16x32_bf16(val, vbh[ct], acc[rt][ct], 0, 0, 0);
        }
      }
      if (pf) {
        unsigned short* nb = smem + (c ^ 1) * 20480;
        union { unsigned short s[4]; uint2 d; } ph, pl;
#pragma unroll
        for (int j = 0; j < 4; ++j) {
          unsigned short h = bf_rne(an[j]);
          ph.s[j] = h;
          pl.s[j] = bf_rne(an[j] - bf_to_f(h));
        }
        *(uint2*)&nb[u * 8 + half * 4] = ph.d;
        *(uint2*)&nb[2048 + u * 8 + half * 4] = pl.d;
      }
      __syncthreads();
      c ^= 1;
    }

    // epilogue: x1 + b1 -> silu -> *w2 -> reduce wave's 64 cols -> atomic x2
    // (unchanged tree: 8 contributors/token = 4 col-wave-groups x 2 n-chunks;
    //  per-contributor: 4-term serial ct sum, then shfl_xor 1,2,4,8)
    float b1v[4], w2v[4];
#pragma unroll
    for (int ct = 0; ct < 4; ++ct) {
      int cidx = nBase + waveC * 64 + ct * 16 + l15;
      b1v[ct] = b1[cidx];
      w2v[ct] = w2[cidx];
    }
#pragma unroll
    for (int rt = 0; rt < 2; ++rt) {
#pragma unroll
      for (int i = 0; i < 4; ++i) {
        float s = 0.f;
#pragma unroll
        for (int ct = 0; ct < 4; ++ct) {
          float x1 = acc[rt][ct][i] + b1v[ct];
          float h1 = x1 / (1.f + expf(-x1));   // silu
          s += h1 * w2v[ct];
        }
        s += __shfl_xor(s, 1, 64);
        s += __shfl_xor(s, 2, 64);
        s += __shfl_xor(s, 4, 64);
        s += __shfl_xor(s, 8, 64);
        if (l15 == 0)
          unsafeAtomicAdd(&x2[tokBase + waveR * 32 + rt * 16 + q * 4 + i], s);
      }
    }
  }
}

// ---------- K3: per-token routing (one wave = one token's 64 experts) -----
__global__ __launch_bounds__(256)
void k_route(const float* __restrict__ lg, const float* __restrict__ x2,
             const float* __restrict__ b2, float* __restrict__ out,
             double* __restrict__ tpe, double* __restrict__ ks_es) {
  const int t = threadIdx.x, wv = t >> 6, e = t & 63;
  const int base = blockIdx.x * 64 + wv * 16;
  const float b2v = b2[0];
  double tacc = 0.0, kacc = 0.0, eacc = 0.0;

  for (int it = 0; it < 16; ++it) {
    const int tok = base + it;
    const size_t idx = (size_t)tok * NE + e;
    float my = lg[idx];
    float xv = x2[tok] + b2v;
    float d = 1.f / (1.f + expf(-xv));
    float kf = 4.f + 8.f * d;
    int ki = (int)rintf(kf);             // round-half-even, matches jnp.round
    ki = min(max(ki, 4), 12);

    int r = 0;  // stable descending rank
#pragma unroll
    for (int s = 1; s < 64; ++s) {
      int src = (e + s) & 63;
      float o = __shfl(my, src, 64);
      r += (o > my || (o == my && src < e)) ? 1 : 0;
    }
    float m = my;
#pragma unroll
    for (int off = 1; off < 64; off <<= 1) m = fmaxf(m, __shfl_xor(m, off, 64));
    float ex = (r < ki) ? expf(my - m) : 0.f;
    float sm = ex;
#pragma unroll
    for (int off = 1; off < 64; off <<= 1) sm += __shfl_xor(sm, off, 64);
    float wgt = ex / sm;
    out[idx] = wgt;

    tacc += (double)wgt;
    kacc += (double)kf;
    eacc += (double)(d * logf(d + 1e-8f) + (1.f - d) * logf(1.f - d + 1e-8f));
  }
  unsafeAtomicAdd(&tpe[e], tacc);
  if (e == 0) {
    unsafeAtomicAdd(&ks_es[0], kacc);
    unsafeAtomicAdd(&ks_es[1], eacc);
  }
}

// ---------- K4: aux loss ----------
__global__ void k_aux(const double* __restrict__ tpe,
                      const double* __restrict__ ks_es,
                      float* __restrict__ out) {
  const int e = threadIdx.x;  // 64 threads
  double x = tpe[e];
  double s = x;
#pragma unroll
  for (int off = 1; off < 64; off <<= 1) s += __shfl_xor(s, off, 64);
  double mean = s / 64.0;
  double dv = x - mean, v = dv * dv;
#pragma unroll
  for (int off = 1; off < 64; off <<= 1) v += __shfl_xor(v, off, 64);
  double var = v / 63.0;                       // ddof=1
  double avgk = ks_es[0] / (double)NTOK;
  double kp = 8.0 - avgk;
  kp = kp > 0.0 ? kp * kp : 0.0;               // relu(BASE_K-avg_k)^2
  double bal = var / (mean + 1e-8);
  double aux = 0.01 * (kp + bal) + 0.001 * (ks_es[1] / (double)NTOK);
  if (e == 0) out[(size_t)NTOK * NE] = (float)aux;
}

// ---------- launch ----------
extern "C" void kernel_launch(void* const* d_in, const int* in_sizes, int n_in,
                              void* d_out, int out_size, void* d_ws, size_t ws_size,
                              hipStream_t stream) {
  const float* hs = (const float*)d_in[0];
  const float* gw = (const float*)d_in[1];
  const float* w1 = (const float*)d_in[2];
  const float* b1 = (const float*)d_in[3];
  const float* w2 = (const float*)d_in[4];
  const float* b2 = (const float*)d_in[5];
  float* out = (float*)d_out;
  char* ws = (char*)d_ws;

  // ws layout (unchanged 8,454,672 B budget):
  //   [0,       4194304)  gate logits lg (fp32, atomically accumulated)
  //   [4194304, 4260368)  x2 / tpe / ks_es  (zeroed together with lg)
  //   [4260368, 6357520)  w1 hi plane (bf16)
  //   [6357520, 8454672)  w1 lo plane (bf16)
  // gw h/m/l planes (786,432 B) staged in d_out; k_route overwrites d_out
  // afterwards (stream-ordered, every element rewritten).
  float* lg = (float*)ws;
  char* tail = ws + 4194304;
  float*  x2    = (float*)tail;              // 65,536 B
  double* tpe   = (double*)(tail + 65536);   // 512 B
  double* ks_es = (double*)(tail + 66048);   // 16 B
  unsigned short* w1h = (unsigned short*)(ws + 4260368);
  unsigned short* w1l = (unsigned short*)(ws + 6357520);
  unsigned short* gwh = (unsigned short*)d_out;
  unsigned short* gwm = gwh + NE * HD;
  unsigned short* gwl = gwm + NE * HD;

  // 1040 zero blocks + 512 w1-split blocks + 64 gw-split blocks
  k_pre<<<1616, 256, 0, stream>>>((uint4*)ws, w1, w1h, w1l, gw, gwh, gwm, gwl);
  k_main<<<1024, 512, 0, stream>>>(hs, gwh, gwm, gwl, lg, w1h, w1l, b1, w2, x2);
  k_route<<<NTOK / 64, 256, 0, stream>>>(lg, x2, b2, out, tpe, ks_es);
  k_aux<<<1, 64, 0, stream>>>(tpe, ks_es, out);
}

// Round 5
// 426.222 us; speedup vs baseline: 1.1665x; 1.1665x over previous
//
#include <hip/hip_runtime.h>
#include <stdint.h>

// Problem constants (match reference)
#define NE   64      // experts
#define HD   2048    // hidden dim
#define ND   512     // difficulty head inner dim
#define NTOK 16384   // B*S = 4*4096

typedef __attribute__((ext_vector_type(4))) float   fv4;
typedef __attribute__((ext_vector_type(8))) short   bf16x8;
typedef __attribute__((ext_vector_type(4))) float   f32x4;

// LDS 16B-unit index: row*4 + (q ^ ((row>>2)&3)).
__device__ inline int swz(int row, int q) {
  return row * 4 + (q ^ ((row >> 2) & 3));
}

// ---------- helpers ----------
__device__ inline unsigned short bf_rne(float x) {
  unsigned int u = __float_as_uint(x);
  return (unsigned short)((u + 0x7FFFu + ((u >> 16) & 1u)) >> 16);
}
__device__ inline float bf_to_f(unsigned short h) {
  return __uint_as_float((unsigned int)h << 16);
}
// exact 3-way truncation split: x == h + m + l (8+8+8 mantissa bits)
__device__ inline void split3(float x, unsigned short& h, unsigned short& m,
                              unsigned short& l) {
  unsigned int u = __float_as_uint(x);
  h = (unsigned short)(u >> 16);
  float r1 = x - __uint_as_float(u & 0xFFFF0000u);
  unsigned int um = __float_as_uint(r1);
  m = (unsigned short)(um >> 16);
  float r2 = r1 - __uint_as_float(um & 0xFFFF0000u);
  l = bf_rne(r2);
}

// async global->LDS 16B copy. Dest = wave-uniform base + lane*16. Source addr
// is per-lane (swizzle folded into the global address).
__device__ inline void gload16(const void* g, void* l) {
  __builtin_amdgcn_global_load_lds(
      (__attribute__((address_space(1))) void*)g,
      (__attribute__((address_space(3))) void*)l, 16, 0, 0);
}

// ---------- K0: fused zero + w1 split + gw split3 (independent writes) ----
__global__ __launch_bounds__(256)
void k_pre(uint4* __restrict__ z16, const float* __restrict__ w1,
           unsigned short* __restrict__ w1h, unsigned short* __restrict__ w1l,
           const float* __restrict__ gw, unsigned short* __restrict__ gh,
           unsigned short* __restrict__ gm, unsigned short* __restrict__ gl) {
  const int b = blockIdx.x, t = threadIdx.x;
  if (b < 1040) {
    // zero lg + x2: 4,259,840 B = 266,240 uint4
    uint4 zz = {0u, 0u, 0u, 0u};
    for (int i = b * 256 + t; i < 266240; i += 1040 * 256) z16[i] = zz;
  } else if (b < 1552) {
    // w1 fp32 -> bf16 hi/lo planes (rne)
    int i = ((b - 1040) * 256 + t) * 8;
    fv4 v0 = *(const fv4*)(w1 + i);
    fv4 v1 = *(const fv4*)(w1 + i + 4);
    union { unsigned short s[8]; uint4 v; } ph, pl;
#pragma unroll
    for (int j = 0; j < 8; ++j) {
      float x = (j < 4) ? v0[j] : v1[j - 4];
      unsigned short h = bf_rne(x);
      ph.s[j] = h;
      pl.s[j] = bf_rne(x - bf_to_f(h));
    }
    *(uint4*)(w1h + i) = ph.v;
    *(uint4*)(w1l + i) = pl.v;
  } else {
    // gw fp32 -> 3 exact bf16 planes (h/m/l truncation split)
    int i = ((b - 1552) * 256 + t) * 8;
    fv4 v0 = *(const fv4*)(gw + i);
    fv4 v1 = *(const fv4*)(gw + i + 4);
    union { unsigned short s[8]; uint4 v; } xh, xm, xl;
#pragma unroll
    for (int j = 0; j < 8; ++j) {
      float x = (j < 4) ? v0[j] : v1[j - 4];
      split3(x, xh.s[j], xm.s[j], xl.s[j]);
    }
    *(uint4*)(gh + i) = xh.v;
    *(uint4*)(gm + i) = xm.v;
    *(uint4*)(gl + i) = xl.v;
  }
}

// ---------- K1: fused gate + difficulty GEMMs (R1-proven body) ----------
// Flat 1024-block grid, XCD-clustered mapping: the 4 blocks sharing one
// 64-token hs tile (gate bx0/bx1 + diff bx0/bx1) get consecutive slots on the
// SAME XCD (xcd = bid&7): gate/diff pipe mixes co-reside per CU and the hs
// tile is read from that XCD's L2 after the first touch. Per-block
// computation (staging, MFMA term order, atomic trees) is bit-identical to
// the R1-passing 223 us kernel.
__global__ __launch_bounds__(256)
void k_main(const float* __restrict__ hs, const unsigned short* __restrict__ gh,
            const unsigned short* __restrict__ gm,
            const unsigned short* __restrict__ gl, float* __restrict__ lg,
            const unsigned short* __restrict__ w1h,
            const unsigned short* __restrict__ w1l, const float* __restrict__ b1,
            const float* __restrict__ w2, float* __restrict__ x2) {
  __shared__ __align__(16) unsigned short smem[20480];  // 40 KB union

  const int t = threadIdx.x;
  const int w = t >> 6, l = t & 63, l15 = l & 15, q = l >> 4;
  const int srow = t >> 2, sq = (t & 3) ^ ((t >> 4) & 3);
  const int bid = blockIdx.x;
  const int xcd = bid & 7, slot = bid >> 3;       // 128 slots per XCD
  const int cluster = (slot >> 2) * 8 + xcd;      // 0..255 token-tiles
  const int sub = slot & 3;                       // gate/diff x bx
  const int kind = sub & 1;
  const int bx = sub >> 1;
  const int tokBase = cluster * 64;

  if (kind == 0) {
    // ================= gate body =================
    unsigned short* sAh = smem;          // 256 units x 8 shorts
    unsigned short* sAm = smem + 2048;
    unsigned short* sAl = smem + 4096;
    unsigned short* sBh = smem + 6144;
    unsigned short* sBm = smem + 8192;
    unsigned short* sBl = smem + 10240;

    const int k0base = bx * (HD / 2);
    const int waveM = w & 1, waveN = w >> 1;

    f32x4 acc[2][2] = {};

    for (int kb = 0; kb < 32; ++kb) {
      const int k0 = k0base + kb * 32;
      // A: fp32 load (issued first), split3 inline, ds_write
      const float* ga = hs + (size_t)(tokBase + srow) * HD + k0 + sq * 8;
      fv4 a0 = *(const fv4*)ga, a1 = *(const fv4*)(ga + 4);
      // B: 3 pre-split planes, async 16B DMA into linear LDS
      {
        const size_t gb = (size_t)srow * HD + k0 + sq * 8;
        gload16(gh + gb, &sBh[t * 8]);
        gload16(gm + gb, &sBm[t * 8]);
        gload16(gl + gb, &sBl[t * 8]);
      }
      {
        union { unsigned short s[8]; uint4 v; } xh, xm, xl;
#pragma unroll
        for (int j = 0; j < 8; ++j) {
          float x = (j < 4) ? a0[j] : a1[j - 4];
          split3(x, xh.s[j], xm.s[j], xl.s[j]);
        }
        *(uint4*)&sAh[t * 8] = xh.v;
        *(uint4*)&sAm[t * 8] = xm.v;
        *(uint4*)&sAl[t * 8] = xl.v;
      }
      __syncthreads();

      bf16x8 ah[2], am[2], al[2], bh[2], bm[2], bl[2];
#pragma unroll
      for (int rt = 0; rt < 2; ++rt) {
        int off = swz(waveM * 32 + rt * 16 + l15, q) * 8;
        ah[rt] = *(const bf16x8*)&sAh[off];
        am[rt] = *(const bf16x8*)&sAm[off];
        al[rt] = *(const bf16x8*)&sAl[off];
      }
#pragma unroll
      for (int ct = 0; ct < 2; ++ct) {
        int off = swz(waveN * 32 + ct * 16 + l15, q) * 8;
        bh[ct] = *(const bf16x8*)&sBh[off];
        bm[ct] = *(const bf16x8*)&sBm[off];
        bl[ct] = *(const bf16x8*)&sBl[off];
      }
#pragma unroll
      for (int rt = 0; rt < 2; ++rt)
#pragma unroll
        for (int ct = 0; ct < 2; ++ct) {
          acc[rt][ct] = __builtin_amdgcn_mfma_f32_16x16x32_bf16(al[rt], bh[ct], acc[rt][ct], 0, 0, 0);
          acc[rt][ct] = __builtin_amdgcn_mfma_f32_16x16x32_bf16(ah[rt], bl[ct], acc[rt][ct], 0, 0, 0);
          acc[rt][ct] = __builtin_amdgcn_mfma_f32_16x16x32_bf16(am[rt], bm[ct], acc[rt][ct], 0, 0, 0);
          acc[rt][ct] = __builtin_amdgcn_mfma_f32_16x16x32_bf16(am[rt], bh[ct], acc[rt][ct], 0, 0, 0);
          acc[rt][ct] = __builtin_amdgcn_mfma_f32_16x16x32_bf16(ah[rt], bm[ct], acc[rt][ct], 0, 0, 0);
          acc[rt][ct] = __builtin_amdgcn_mfma_f32_16x16x32_bf16(ah[rt], bh[ct], acc[rt][ct], 0, 0, 0);
        }
      __syncthreads();
    }

#pragma unroll
    for (int rt = 0; rt < 2; ++rt)
#pragma unroll
      for (int ct = 0; ct < 2; ++ct)
#pragma unroll
        for (int i = 0; i < 4; ++i)
          unsafeAtomicAdd(&lg[(size_t)(tokBase + waveM * 32 + rt * 16 + q * 4 + i) * NE +
                              waveN * 32 + ct * 16 + l15], acc[rt][ct][i]);
  } else {
    // ================= diff body =================
    unsigned short* sAh = smem;           // 256 units
    unsigned short* sAl = smem + 2048;
    unsigned short* sBh = smem + 4096;    // 1024 units
    unsigned short* sBl = smem + 12288;

    const int nBase = bx * 256;

    f32x4 acc[4][4] = {};

    for (int kb = 0; kb < HD / 32; ++kb) {
      const int k0 = kb * 32;
      // A: fp32 load (issued first), rne hi/lo split, ds_write
      const float* g = hs + (size_t)(tokBase + srow) * HD + k0 + sq * 8;
      fv4 v0 = *(const fv4*)g, v1 = *(const fv4*)(g + 4);
      // B: 1024 units per plane, 4 per thread, async 16B DMA
#pragma unroll
      for (int j = 0; j < 4; ++j) {
        int s = t + j * 256;
        int brow = s >> 2, bq = (s & 3) ^ ((s >> 4) & 3);
        const size_t gb = (size_t)(nBase + brow) * HD + k0 + bq * 8;
        gload16(w1h + gb, &sBh[s * 8]);
        gload16(w1l + gb, &sBl[s * 8]);
      }
      {
        union { unsigned short s[8]; uint4 v; } ph, pl;
#pragma unroll
        for (int jj = 0; jj < 8; ++jj) {
          float x = (jj < 4) ? v0[jj] : v1[jj - 4];
          unsigned short h = bf_rne(x);
          ph.s[jj] = h;
          pl.s[jj] = bf_rne(x - bf_to_f(h));
        }
        *(uint4*)&sAh[t * 8] = ph.v;
        *(uint4*)&sAl[t * 8] = pl.v;
      }
      __syncthreads();

      bf16x8 bh[4], bl[4];
#pragma unroll
      for (int ct = 0; ct < 4; ++ct) {
        int off = swz(w * 64 + ct * 16 + l15, q) * 8;
        bh[ct] = *(const bf16x8*)&sBh[off];
        bl[ct] = *(const bf16x8*)&sBl[off];
      }
#pragma unroll
      for (int rt = 0; rt < 4; ++rt) {
        int off = swz(rt * 16 + l15, q) * 8;
        bf16x8 ah = *(const bf16x8*)&sAh[off];
        bf16x8 al = *(const bf16x8*)&sAl[off];
#pragma unroll
        for (int ct = 0; ct < 4; ++ct) {
          acc[rt][ct] = __builtin_amdgcn_mfma_f32_16x16x32_bf16(ah, bh[ct], acc[rt][ct], 0, 0, 0);
          acc[rt][ct] = __builtin_amdgcn_mfma_f32_16x16x32_bf16(ah, bl[ct], acc[rt][ct], 0, 0, 0);
          acc[rt][ct] = __builtin_amdgcn_mfma_f32_16x16x32_bf16(al, bh[ct], acc[rt][ct], 0, 0, 0);
        }
      }
      __syncthreads();
    }

    // epilogue: x1 + b1 -> silu -> *w2 -> reduce wave's 64 cols -> atomic x2
    // (unchanged tree: 8 contributors/token = 4 col-waves x 2 n-chunks)
    float b1v[4], w2v[4];
#pragma unroll
    for (int ct = 0; ct < 4; ++ct) {
      int cidx = nBase + w * 64 + ct * 16 + l15;
      b1v[ct] = b1[cidx];
      w2v[ct] = w2[cidx];
    }
#pragma unroll
    for (int rt = 0; rt < 4; ++rt) {
#pragma unroll
      for (int i = 0; i < 4; ++i) {
        float s = 0.f;
#pragma unroll
        for (int ct = 0; ct < 4; ++ct) {
          float x1 = acc[rt][ct][i] + b1v[ct];
          float h1 = x1 / (1.f + expf(-x1));   // silu
          s += h1 * w2v[ct];
        }
        s += __shfl_xor(s, 1, 64);
        s += __shfl_xor(s, 2, 64);
        s += __shfl_xor(s, 4, 64);
        s += __shfl_xor(s, 8, 64);
        if (l15 == 0)
          unsafeAtomicAdd(&x2[tokBase + rt * 16 + q * 4 + i], s);
      }
    }
  }
}

// ---------- K3: per-token routing, one token PER WAVE, atomic-free --------
// 1024 blocks x 1024 thr (16 waves): full occupancy vs old 1 wave/SIMD.
// Per-token math (rank loop, shuffle trees, softmax) instruction-identical
// to the proven kernel -> out[] bit-identical. tpe/ks reductions become
// per-block partials in ws (f64 regroup only affects the aux scalar ~1e-15).
__global__ __launch_bounds__(1024)
void k_route(const float* __restrict__ lg, const float* __restrict__ x2,
             const float* __restrict__ b2, float* __restrict__ out,
             double* __restrict__ tpe_part, double* __restrict__ ks_part) {
  __shared__ double sdt[16 * 64];
  __shared__ double skv[16], sev[16];
  const int t = threadIdx.x, wv = t >> 6, e = t & 63;
  const int tok = blockIdx.x * 16 + wv;
  const float b2v = b2[0];

  const size_t idx = (size_t)tok * NE + e;
  float my = lg[idx];
  float xv = x2[tok] + b2v;
  float d = 1.f / (1.f + expf(-xv));
  float kf = 4.f + 8.f * d;
  int ki = (int)rintf(kf);             // round-half-even, matches jnp.round
  ki = min(max(ki, 4), 12);

  int r = 0;  // stable descending rank
#pragma unroll
  for (int s = 1; s < 64; ++s) {
    int src = (e + s) & 63;
    float o = __shfl(my, src, 64);
    r += (o > my || (o == my && src < e)) ? 1 : 0;
  }
  float m = my;
#pragma unroll
  for (int off = 1; off < 64; off <<= 1) m = fmaxf(m, __shfl_xor(m, off, 64));
  float ex = (r < ki) ? expf(my - m) : 0.f;
  float sm = ex;
#pragma unroll
  for (int off = 1; off < 64; off <<= 1) sm += __shfl_xor(sm, off, 64);
  float wgt = ex / sm;
  out[idx] = wgt;

  sdt[wv * 64 + e] = (double)wgt;
  if (e == 0) {
    skv[wv] = (double)kf;
    sev[wv] = (double)(d * logf(d + 1e-8f) + (1.f - d) * logf(1.f - d + 1e-8f));
  }
  __syncthreads();
  if (t < 64) {
    double s = 0.0;
#pragma unroll
    for (int wq = 0; wq < 16; ++wq) s += sdt[wq * 64 + t];
    tpe_part[(size_t)blockIdx.x * 64 + t] = s;
  } else if (t == 64) {
    double ks = 0.0, es = 0.0;
#pragma unroll
    for (int wq = 0; wq < 16; ++wq) { ks += skv[wq]; es += sev[wq]; }
    ks_part[blockIdx.x * 2 + 0] = ks;
    ks_part[blockIdx.x * 2 + 1] = es;
  }
}

// ---------- K4: aux loss (two-stage reduce of per-block partials) ----------
__global__ __launch_bounds__(1024)
void k_aux(const double* __restrict__ tpe_part,
           const double* __restrict__ ks_part, float* __restrict__ out) {
  __shared__ double sred[16 * 64];
  __shared__ double sk[16], se2[16];
  const int t = threadIdx.x, e = t & 63, chunk = t >> 6;  // 16 chunks

  // tpe: each thread sums 64 block-partials of its expert
  double s = 0.0;
  for (int b = 0; b < 64; ++b)
    s += tpe_part[(size_t)(chunk * 64 + b) * 64 + e];
  sred[chunk * 64 + e] = s;

  // ks/es: thread t owns block t (1024 blocks), wave-reduce then LDS
  double k0 = ks_part[t * 2 + 0];
  double e0 = ks_part[t * 2 + 1];
#pragma unroll
  for (int off = 1; off < 64; off <<= 1) {
    k0 += __shfl_xor(k0, off, 64);
    e0 += __shfl_xor(e0, off, 64);
  }
  if (e == 0) { sk[chunk] = k0; se2[chunk] = e0; }
  __syncthreads();

  if (t < 64) {
    double x = 0.0;
#pragma unroll
    for (int c = 0; c < 16; ++c) x += sred[c * 64 + t];
    // x = tokens_per_expert[t]
    double ssum = x;
#pragma unroll
    for (int off = 1; off < 64; off <<= 1) ssum += __shfl_xor(ssum, off, 64);
    double mean = ssum / 64.0;
    double dv = x - mean, v = dv * dv;
#pragma unroll
    for (int off = 1; off < 64; off <<= 1) v += __shfl_xor(v, off, 64);
    double var = v / 63.0;                       // ddof=1
    if (t == 0) {
      double ksum = 0.0, esum = 0.0;
#pragma unroll
      for (int c = 0; c < 16; ++c) { ksum += sk[c]; esum += se2[c]; }
      double avgk = ksum / (double)NTOK;
      double kp = 8.0 - avgk;
      kp = kp > 0.0 ? kp * kp : 0.0;             // relu(BASE_K-avg_k)^2
      double bal = var / (mean + 1e-8);
      double aux = 0.01 * (kp + bal) + 0.001 * (esum / (double)NTOK);
      out[(size_t)NTOK * NE] = (float)aux;
    }
  }
}

// ---------- launch ----------
extern "C" void kernel_launch(void* const* d_in, const int* in_sizes, int n_in,
                              void* d_out, int out_size, void* d_ws, size_t ws_size,
                              hipStream_t stream) {
  const float* hs = (const float*)d_in[0];
  const float* gw = (const float*)d_in[1];
  const float* w1 = (const float*)d_in[2];
  const float* b1 = (const float*)d_in[3];
  const float* w2 = (const float*)d_in[4];
  const float* b2 = (const float*)d_in[5];
  float* out = (float*)d_out;
  char* ws = (char*)d_ws;

  // ws layout (within the 8,454,672 B budget):
  //   [0,       4194304)  gate logits lg (fp32, atomically accumulated)
  //   [4194304, 4259840)  x2 (zeroed together with lg)
  //   [4260368, 6357520)  w1 hi plane (bf16) -- dead after k_main; overlaid
  //                       by k_route partials: tpe_part 524,288 B at
  //                       4260368, ks_part 16,384 B at 4784656
  //   [6357520, 8454672)  w1 lo plane (bf16)
  // gw h/m/l planes (786,432 B) staged in d_out; k_route overwrites d_out
  // afterwards (stream-ordered, every element rewritten).
  float* lg = (float*)ws;
  float* x2 = (float*)(ws + 4194304);
  unsigned short* w1h = (unsigned short*)(ws + 4260368);
  unsigned short* w1l = (unsigned short*)(ws + 6357520);
  double* tpe_part = (double*)(ws + 4260368);   // overlays dead w1h
  double* ks_part  = (double*)(ws + 4784656);
  unsigned short* gwh = (unsigned short*)d_out;
  unsigned short* gwm = gwh + NE * HD;
  unsigned short* gwl = gwm + NE * HD;

  // 1040 zero blocks + 512 w1-split blocks + 64 gw-split blocks
  k_pre<<<1616, 256, 0, stream>>>((uint4*)ws, w1, w1h, w1l, gw, gwh, gwm, gwl);
  k_main<<<1024, 256, 0, stream>>>(hs, gwh, gwm, gwl, lg, w1h, w1l, b1, w2, x2);
  k_route<<<NTOK / 16, 1024, 0, stream>>>(lg, x2, b2, out, tpe_part, ks_part);
  k_aux<<<1, 1024, 0, stream>>>(tpe_part, ks_part, out);
}

// Round 6
// 385.638 us; speedup vs baseline: 1.2893x; 1.1052x over previous
//
#include <hip/hip_runtime.h>
#include <stdint.h>

// Problem constants (match reference)
#define NE   64      // experts
#define HD   2048    // hidden dim
#define ND   512     // difficulty head inner dim
#define NTOK 16384   // B*S = 4*4096

typedef __attribute__((ext_vector_type(4))) float   fv4;
typedef __attribute__((ext_vector_type(8))) short   bf16x8;
typedef __attribute__((ext_vector_type(4))) float   f32x4;

// LDS 16B-unit index: row*4 + (q ^ ((row>>2)&3)).
__device__ inline int swz(int row, int q) {
  return row * 4 + (q ^ ((row >> 2) & 3));
}

// ---------- helpers ----------
__device__ inline unsigned short bf_rne(float x) {
  unsigned int u = __float_as_uint(x);
  return (unsigned short)((u + 0x7FFFu + ((u >> 16) & 1u)) >> 16);
}
__device__ inline float bf_to_f(unsigned short h) {
  return __uint_as_float((unsigned int)h << 16);
}
// exact 3-way truncation split: x == h + m + l (8+8+8 mantissa bits)
__device__ inline void split3(float x, unsigned short& h, unsigned short& m,
                              unsigned short& l) {
  unsigned int u = __float_as_uint(x);
  h = (unsigned short)(u >> 16);
  float r1 = x - __uint_as_float(u & 0xFFFF0000u);
  unsigned int um = __float_as_uint(r1);
  m = (unsigned short)(um >> 16);
  float r2 = r1 - __uint_as_float(um & 0xFFFF0000u);
  l = bf_rne(r2);
}

// async global->LDS 16B copy. Dest = wave-uniform base + lane*16. Source addr
// is per-lane (swizzle folded into the global address).
__device__ inline void gload16(const void* g, void* l) {
  __builtin_amdgcn_global_load_lds(
      (__attribute__((address_space(1))) void*)g,
      (__attribute__((address_space(3))) void*)l, 16, 0, 0);
}

// ---------- K0: fused zero + w1 split + gw split3 (independent writes) ----
__global__ __launch_bounds__(256)
void k_pre(uint4* __restrict__ z16, const float* __restrict__ w1,
           unsigned short* __restrict__ w1h, unsigned short* __restrict__ w1l,
           const float* __restrict__ gw, unsigned short* __restrict__ gh,
           unsigned short* __restrict__ gm, unsigned short* __restrict__ gl) {
  const int b = blockIdx.x, t = threadIdx.x;
  if (b < 1040) {
    // zero lg + x2: 4,259,840 B = 266,240 uint4
    uint4 zz = {0u, 0u, 0u, 0u};
    for (int i = b * 256 + t; i < 266240; i += 1040 * 256) z16[i] = zz;
  } else if (b < 1552) {
    // w1 fp32 -> bf16 hi/lo planes (rne)
    int i = ((b - 1040) * 256 + t) * 8;
    fv4 v0 = *(const fv4*)(w1 + i);
    fv4 v1 = *(const fv4*)(w1 + i + 4);
    union { unsigned short s[8]; uint4 v; } ph, pl;
#pragma unroll
    for (int j = 0; j < 8; ++j) {
      float x = (j < 4) ? v0[j] : v1[j - 4];
      unsigned short h = bf_rne(x);
      ph.s[j] = h;
      pl.s[j] = bf_rne(x - bf_to_f(h));
    }
    *(uint4*)(w1h + i) = ph.v;
    *(uint4*)(w1l + i) = pl.v;
  } else {
    // gw fp32 -> 3 exact bf16 planes (h/m/l truncation split)
    int i = ((b - 1552) * 256 + t) * 8;
    fv4 v0 = *(const fv4*)(gw + i);
    fv4 v1 = *(const fv4*)(gw + i + 4);
    union { unsigned short s[8]; uint4 v; } xh, xm, xl;
#pragma unroll
    for (int j = 0; j < 8; ++j) {
      float x = (j < 4) ? v0[j] : v1[j - 4];
      split3(x, xh.s[j], xm.s[j], xl.s[j]);
    }
    *(uint4*)(gh + i) = xh.v;
    *(uint4*)(gm + i) = xm.v;
    *(uint4*)(gl + i) = xl.v;
  }
}

// ---------- K1: fused gate + difficulty GEMMs (R1-proven body + grid) -----
// Grid dim3(2, 256, 2), z-major dispatch: all 512 gate blocks (z=0) issue
// before the 512 diff blocks (z=1). R5's XCD-clustered interleave REGRESSED
// (223 -> 286 us: occupancy 22.6 -> 15.8% from gate/diff length imbalance;
// FETCH improved 207 -> 160 MB but the kernel is not BW-bound, so locality
// bought nothing). This exact configuration measured 223 us in R1.
__global__ __launch_bounds__(256)
void k_main(const float* __restrict__ hs, const unsigned short* __restrict__ gh,
            const unsigned short* __restrict__ gm,
            const unsigned short* __restrict__ gl, float* __restrict__ lg,
            const unsigned short* __restrict__ w1h,
            const unsigned short* __restrict__ w1l, const float* __restrict__ b1,
            const float* __restrict__ w2, float* __restrict__ x2) {
  __shared__ __align__(16) unsigned short smem[20480];  // 40 KB union

  const int t = threadIdx.x;
  const int w = t >> 6, l = t & 63, l15 = l & 15, q = l >> 4;
  const int srow = t >> 2, sq = (t & 3) ^ ((t >> 4) & 3);
  const int tokBase = blockIdx.y * 64;

  if (blockIdx.z == 0) {
    // ================= gate body =================
    unsigned short* sAh = smem;          // 256 units x 8 shorts
    unsigned short* sAm = smem + 2048;
    unsigned short* sAl = smem + 4096;
    unsigned short* sBh = smem + 6144;
    unsigned short* sBm = smem + 8192;
    unsigned short* sBl = smem + 10240;

    const int k0base = blockIdx.x * (HD / 2);
    const int waveM = w & 1, waveN = w >> 1;

    f32x4 acc[2][2] = {};

    for (int kb = 0; kb < 32; ++kb) {
      const int k0 = k0base + kb * 32;
      // A: fp32 load (issued first), split3 inline, ds_write
      const float* ga = hs + (size_t)(tokBase + srow) * HD + k0 + sq * 8;
      fv4 a0 = *(const fv4*)ga, a1 = *(const fv4*)(ga + 4);
      // B: 3 pre-split planes, async 16B DMA into linear LDS
      {
        const size_t gb = (size_t)srow * HD + k0 + sq * 8;
        gload16(gh + gb, &sBh[t * 8]);
        gload16(gm + gb, &sBm[t * 8]);
        gload16(gl + gb, &sBl[t * 8]);
      }
      {
        union { unsigned short s[8]; uint4 v; } xh, xm, xl;
#pragma unroll
        for (int j = 0; j < 8; ++j) {
          float x = (j < 4) ? a0[j] : a1[j - 4];
          split3(x, xh.s[j], xm.s[j], xl.s[j]);
        }
        *(uint4*)&sAh[t * 8] = xh.v;
        *(uint4*)&sAm[t * 8] = xm.v;
        *(uint4*)&sAl[t * 8] = xl.v;
      }
      __syncthreads();

      bf16x8 ah[2], am[2], al[2], bh[2], bm[2], bl[2];
#pragma unroll
      for (int rt = 0; rt < 2; ++rt) {
        int off = swz(waveM * 32 + rt * 16 + l15, q) * 8;
        ah[rt] = *(const bf16x8*)&sAh[off];
        am[rt] = *(const bf16x8*)&sAm[off];
        al[rt] = *(const bf16x8*)&sAl[off];
      }
#pragma unroll
      for (int ct = 0; ct < 2; ++ct) {
        int off = swz(waveN * 32 + ct * 16 + l15, q) * 8;
        bh[ct] = *(const bf16x8*)&sBh[off];
        bm[ct] = *(const bf16x8*)&sBm[off];
        bl[ct] = *(const bf16x8*)&sBl[off];
      }
#pragma unroll
      for (int rt = 0; rt < 2; ++rt)
#pragma unroll
        for (int ct = 0; ct < 2; ++ct) {
          acc[rt][ct] = __builtin_amdgcn_mfma_f32_16x16x32_bf16(al[rt], bh[ct], acc[rt][ct], 0, 0, 0);
          acc[rt][ct] = __builtin_amdgcn_mfma_f32_16x16x32_bf16(ah[rt], bl[ct], acc[rt][ct], 0, 0, 0);
          acc[rt][ct] = __builtin_amdgcn_mfma_f32_16x16x32_bf16(am[rt], bm[ct], acc[rt][ct], 0, 0, 0);
          acc[rt][ct] = __builtin_amdgcn_mfma_f32_16x16x32_bf16(am[rt], bh[ct], acc[rt][ct], 0, 0, 0);
          acc[rt][ct] = __builtin_amdgcn_mfma_f32_16x16x32_bf16(ah[rt], bm[ct], acc[rt][ct], 0, 0, 0);
          acc[rt][ct] = __builtin_amdgcn_mfma_f32_16x16x32_bf16(ah[rt], bh[ct], acc[rt][ct], 0, 0, 0);
        }
      __syncthreads();
    }

#pragma unroll
    for (int rt = 0; rt < 2; ++rt)
#pragma unroll
      for (int ct = 0; ct < 2; ++ct)
#pragma unroll
        for (int i = 0; i < 4; ++i)
          unsafeAtomicAdd(&lg[(size_t)(tokBase + waveM * 32 + rt * 16 + q * 4 + i) * NE +
                              waveN * 32 + ct * 16 + l15], acc[rt][ct][i]);
  } else {
    // ================= diff body =================
    unsigned short* sAh = smem;           // 256 units
    unsigned short* sAl = smem + 2048;
    unsigned short* sBh = smem + 4096;    // 1024 units
    unsigned short* sBl = smem + 12288;

    const int nBase = blockIdx.x * 256;

    f32x4 acc[4][4] = {};

    for (int kb = 0; kb < HD / 32; ++kb) {
      const int k0 = kb * 32;
      // A: fp32 load (issued first), rne hi/lo split, ds_write
      const float* g = hs + (size_t)(tokBase + srow) * HD + k0 + sq * 8;
      fv4 v0 = *(const fv4*)g, v1 = *(const fv4*)(g + 4);
      // B: 1024 units per plane, 4 per thread, async 16B DMA
#pragma unroll
      for (int j = 0; j < 4; ++j) {
        int s = t + j * 256;
        int brow = s >> 2, bq = (s & 3) ^ ((s >> 4) & 3);
        const size_t gb = (size_t)(nBase + brow) * HD + k0 + bq * 8;
        gload16(w1h + gb, &sBh[s * 8]);
        gload16(w1l + gb, &sBl[s * 8]);
      }
      {
        union { unsigned short s[8]; uint4 v; } ph, pl;
#pragma unroll
        for (int jj = 0; jj < 8; ++jj) {
          float x = (jj < 4) ? v0[jj] : v1[jj - 4];
          unsigned short h = bf_rne(x);
          ph.s[jj] = h;
          pl.s[jj] = bf_rne(x - bf_to_f(h));
        }
        *(uint4*)&sAh[t * 8] = ph.v;
        *(uint4*)&sAl[t * 8] = pl.v;
      }
      __syncthreads();

      bf16x8 bh[4], bl[4];
#pragma unroll
      for (int ct = 0; ct < 4; ++ct) {
        int off = swz(w * 64 + ct * 16 + l15, q) * 8;
        bh[ct] = *(const bf16x8*)&sBh[off];
        bl[ct] = *(const bf16x8*)&sBl[off];
      }
#pragma unroll
      for (int rt = 0; rt < 4; ++rt) {
        int off = swz(rt * 16 + l15, q) * 8;
        bf16x8 ah = *(const bf16x8*)&sAh[off];
        bf16x8 al = *(const bf16x8*)&sAl[off];
#pragma unroll
        for (int ct = 0; ct < 4; ++ct) {
          acc[rt][ct] = __builtin_amdgcn_mfma_f32_16x16x32_bf16(ah, bh[ct], acc[rt][ct], 0, 0, 0);
          acc[rt][ct] = __builtin_amdgcn_mfma_f32_16x16x32_bf16(ah, bl[ct], acc[rt][ct], 0, 0, 0);
          acc[rt][ct] = __builtin_amdgcn_mfma_f32_16x16x32_bf16(al, bh[ct], acc[rt][ct], 0, 0, 0);
        }
      }
      __syncthreads();
    }

    // epilogue: x1 + b1 -> silu -> *w2 -> reduce wave's 64 cols -> atomic x2
    // (unchanged tree: 8 contributors/token = 4 col-waves x 2 n-chunks)
    float b1v[4], w2v[4];
#pragma unroll
    for (int ct = 0; ct < 4; ++ct) {
      int cidx = nBase + w * 64 + ct * 16 + l15;
      b1v[ct] = b1[cidx];
      w2v[ct] = w2[cidx];
    }
#pragma unroll
    for (int rt = 0; rt < 4; ++rt) {
#pragma unroll
      for (int i = 0; i < 4; ++i) {
        float s = 0.f;
#pragma unroll
        for (int ct = 0; ct < 4; ++ct) {
          float x1 = acc[rt][ct][i] + b1v[ct];
          float h1 = x1 / (1.f + expf(-x1));   // silu
          s += h1 * w2v[ct];
        }
        s += __shfl_xor(s, 1, 64);
        s += __shfl_xor(s, 2, 64);
        s += __shfl_xor(s, 4, 64);
        s += __shfl_xor(s, 8, 64);
        if (l15 == 0)
          unsafeAtomicAdd(&x2[tokBase + rt * 16 + q * 4 + i], s);
      }
    }
  }
}

// ---------- K3: per-token routing, one token PER WAVE, atomic-free --------
// (R5-proven: saved ~73 us vs the 16-token-serial 1-wave/SIMD version.)
// Per-token math (rank loop, shuffle trees, softmax) instruction-identical
// -> out[] bit-identical. tpe/ks reductions are per-block partials in ws.
__global__ __launch_bounds__(1024)
void k_route(const float* __restrict__ lg, const float* __restrict__ x2,
             const float* __restrict__ b2, float* __restrict__ out,
             double* __restrict__ tpe_part, double* __restrict__ ks_part) {
  __shared__ double sdt[16 * 64];
  __shared__ double skv[16], sev[16];
  const int t = threadIdx.x, wv = t >> 6, e = t & 63;
  const int tok = blockIdx.x * 16 + wv;
  const float b2v = b2[0];

  const size_t idx = (size_t)tok * NE + e;
  float my = lg[idx];
  float xv = x2[tok] + b2v;
  float d = 1.f / (1.f + expf(-xv));
  float kf = 4.f + 8.f * d;
  int ki = (int)rintf(kf);             // round-half-even, matches jnp.round
  ki = min(max(ki, 4), 12);

  int r = 0;  // stable descending rank
#pragma unroll
  for (int s = 1; s < 64; ++s) {
    int src = (e + s) & 63;
    float o = __shfl(my, src, 64);
    r += (o > my || (o == my && src < e)) ? 1 : 0;
  }
  float m = my;
#pragma unroll
  for (int off = 1; off < 64; off <<= 1) m = fmaxf(m, __shfl_xor(m, off, 64));
  float ex = (r < ki) ? expf(my - m) : 0.f;
  float sm = ex;
#pragma unroll
  for (int off = 1; off < 64; off <<= 1) sm += __shfl_xor(sm, off, 64);
  float wgt = ex / sm;
  out[idx] = wgt;

  sdt[wv * 64 + e] = (double)wgt;
  if (e == 0) {
    skv[wv] = (double)kf;
    sev[wv] = (double)(d * logf(d + 1e-8f) + (1.f - d) * logf(1.f - d + 1e-8f));
  }
  __syncthreads();
  if (t < 64) {
    double s = 0.0;
#pragma unroll
    for (int wq = 0; wq < 16; ++wq) s += sdt[wq * 64 + t];
    tpe_part[(size_t)blockIdx.x * 64 + t] = s;
  } else if (t == 64) {
    double ks = 0.0, es = 0.0;
#pragma unroll
    for (int wq = 0; wq < 16; ++wq) { ks += skv[wq]; es += sev[wq]; }
    ks_part[blockIdx.x * 2 + 0] = ks;
    ks_part[blockIdx.x * 2 + 1] = es;
  }
}

// ---------- K4: aux loss (two-stage reduce of per-block partials) ----------
__global__ __launch_bounds__(1024)
void k_aux(const double* __restrict__ tpe_part,
           const double* __restrict__ ks_part, float* __restrict__ out) {
  __shared__ double sred[16 * 64];
  __shared__ double sk[16], se2[16];
  const int t = threadIdx.x, e = t & 63, chunk = t >> 6;  // 16 chunks

  // tpe: each thread sums 64 block-partials of its expert
  double s = 0.0;
  for (int b = 0; b < 64; ++b)
    s += tpe_part[(size_t)(chunk * 64 + b) * 64 + e];
  sred[chunk * 64 + e] = s;

  // ks/es: thread t owns block t (1024 blocks), wave-reduce then LDS
  double k0 = ks_part[t * 2 + 0];
  double e0 = ks_part[t * 2 + 1];
#pragma unroll
  for (int off = 1; off < 64; off <<= 1) {
    k0 += __shfl_xor(k0, off, 64);
    e0 += __shfl_xor(e0, off, 64);
  }
  if (e == 0) { sk[chunk] = k0; se2[chunk] = e0; }
  __syncthreads();

  if (t < 64) {
    double x = 0.0;
#pragma unroll
    for (int c = 0; c < 16; ++c) x += sred[c * 64 + t];
    // x = tokens_per_expert[t]
    double ssum = x;
#pragma unroll
    for (int off = 1; off < 64; off <<= 1) ssum += __shfl_xor(ssum, off, 64);
    double mean = ssum / 64.0;
    double dv = x - mean, v = dv * dv;
#pragma unroll
    for (int off = 1; off < 64; off <<= 1) v += __shfl_xor(v, off, 64);
    double var = v / 63.0;                       // ddof=1
    if (t == 0) {
      double ksum = 0.0, esum = 0.0;
#pragma unroll
      for (int c = 0; c < 16; ++c) { ksum += sk[c]; esum += se2[c]; }
      double avgk = ksum / (double)NTOK;
      double kp = 8.0 - avgk;
      kp = kp > 0.0 ? kp * kp : 0.0;             // relu(BASE_K-avg_k)^2
      double bal = var / (mean + 1e-8);
      double aux = 0.01 * (kp + bal) + 0.001 * (esum / (double)NTOK);
      out[(size_t)NTOK * NE] = (float)aux;
    }
  }
}

// ---------- launch ----------
extern "C" void kernel_launch(void* const* d_in, const int* in_sizes, int n_in,
                              void* d_out, int out_size, void* d_ws, size_t ws_size,
                              hipStream_t stream) {
  const float* hs = (const float*)d_in[0];
  const float* gw = (const float*)d_in[1];
  const float* w1 = (const float*)d_in[2];
  const float* b1 = (const float*)d_in[3];
  const float* w2 = (const float*)d_in[4];
  const float* b2 = (const float*)d_in[5];
  float* out = (float*)d_out;
  char* ws = (char*)d_ws;

  // ws layout (within the 8,454,672 B budget):
  //   [0,       4194304)  gate logits lg (fp32, atomically accumulated)
  //   [4194304, 4259840)  x2 (zeroed together with lg)
  //   [4260368, 6357520)  w1 hi plane (bf16) -- dead after k_main; overlaid
  //                       by k_route partials: tpe_part 524,288 B at
  //                       4260368, ks_part 16,384 B at 4784656
  //   [6357520, 8454672)  w1 lo plane (bf16)
  // gw h/m/l planes (786,432 B) staged in d_out; k_route overwrites d_out
  // afterwards (stream-ordered, every element rewritten).
  float* lg = (float*)ws;
  float* x2 = (float*)(ws + 4194304);
  unsigned short* w1h = (unsigned short*)(ws + 4260368);
  unsigned short* w1l = (unsigned short*)(ws + 6357520);
  double* tpe_part = (double*)(ws + 4260368);   // overlays dead w1h
  double* ks_part  = (double*)(ws + 4784656);
  unsigned short* gwh = (unsigned short*)d_out;
  unsigned short* gwm = gwh + NE * HD;
  unsigned short* gwl = gwm + NE * HD;

  // 1040 zero blocks + 512 w1-split blocks + 64 gw-split blocks
  k_pre<<<1616, 256, 0, stream>>>((uint4*)ws, w1, w1h, w1l, gw, gwh, gwm, gwl);
  k_main<<<dim3(2, NTOK / 64, 2), 256, 0, stream>>>(hs, gwh, gwm, gwl, lg,
                                                    w1h, w1l, b1, w2, x2);
  k_route<<<NTOK / 16, 1024, 0, stream>>>(lg, x2, b2, out, tpe_part, ks_part);
  k_aux<<<1, 1024, 0, stream>>>(tpe_part, ks_part, out);
}